// Round 1
// baseline (1535.506 us; speedup 1.0000x reference)
//
#include <hip/hip_runtime.h>

#define DD 128   // feature dim
#define NB 8     // num bases

// ---------------------------------------------------------------------------
// GEMM: for blockIdx.y = m in [0,9):
//   m < 8 : hb[n, m, :]   = h[n,:] @ bases[m]          (basis transform)
//   m == 8: selfout[n, :] = h[n,:] @ loop_w + bias     (self-loop, init out)
// h rows optionally indirected through ids (h_ids gather, layer 1 only).
// Block tile: 64 nodes x 128 outputs, 256 threads, 4x8 register tile/thread.
// ---------------------------------------------------------------------------
__global__ __launch_bounds__(256) void k_gemm(
    const float* __restrict__ h, const int* __restrict__ ids,
    const float* __restrict__ bases, const float* __restrict__ loopw,
    const float* __restrict__ bias,
    float* __restrict__ hb, float* __restrict__ selfout, int N)
{
  __shared__ float sW[32][128];   // 16 KB: W k-chunk
  __shared__ float sH[32][64];    // 8 KB: h chunk, transposed [k][node]

  const int m = blockIdx.y;
  const float* __restrict__ W = (m < NB) ? (bases + (size_t)m * DD * DD) : loopw;
  const int n0 = blockIdx.x * 64;
  const int t  = threadIdx.x;
  const int tx = t & 15;          // output group: o = tx*8 .. tx*8+8
  const int ty = t >> 4;          // node group:   n = n0 + ty*4 .. +4

  float acc[4][8] = {};

  for (int k0 = 0; k0 < DD; k0 += 32) {
    // stage W chunk (rows k0..k0+32, all 128 cols), linear float4 copy
    for (int i = t; i < 1024; i += 256)
      ((float4*)sW)[i] = ((const float4*)(W + (size_t)k0 * DD))[i];
    // stage h chunk transposed: sH[kk][node]
    {
      int nn = t >> 2;
      int kk = (t & 3) * 8;
      int row = n0 + nn; if (row >= N) row = N - 1;   // clamp (writes guarded)
      if (ids) row = ids[row];
      const float* hp = h + (size_t)row * DD + k0 + kk;
      float4 v0 = *(const float4*)hp;
      float4 v1 = *(const float4*)(hp + 4);
      sH[kk+0][nn]=v0.x; sH[kk+1][nn]=v0.y; sH[kk+2][nn]=v0.z; sH[kk+3][nn]=v0.w;
      sH[kk+4][nn]=v1.x; sH[kk+5][nn]=v1.y; sH[kk+6][nn]=v1.z; sH[kk+7][nn]=v1.w;
    }
    __syncthreads();
    #pragma unroll
    for (int kk = 0; kk < 32; kk++) {
      float hv[4], wv[8];
      *(float4*)hv     = *(const float4*)&sH[kk][ty*4];
      *(float4*)&wv[0] = *(const float4*)&sW[kk][tx*8];
      *(float4*)&wv[4] = *(const float4*)&sW[kk][tx*8+4];
      #pragma unroll
      for (int a = 0; a < 4; a++)
        #pragma unroll
        for (int bb = 0; bb < 8; bb++)
          acc[a][bb] += hv[a] * wv[bb];
    }
    __syncthreads();
  }

  #pragma unroll
  for (int a = 0; a < 4; a++) {
    int n = n0 + ty*4 + a;
    if (n >= N) continue;
    if (m < NB) {
      float4* dst = (float4*)&hb[((size_t)n * NB + m) * DD + tx*8];
      dst[0] = *(float4*)&acc[a][0];
      dst[1] = *(float4*)&acc[a][4];
    } else {
      float o[8];
      #pragma unroll
      for (int bb = 0; bb < 8; bb++) o[bb] = acc[a][bb] + bias[tx*8 + bb];
      float4* dst = (float4*)&selfout[(size_t)n * DD + tx*8];
      dst[0] = *(float4*)&o[0];
      dst[1] = *(float4*)&o[4];
    }
  }
}

// ---------------------------------------------------------------------------
// Edge kernel: one wave per edge. Gather hb[src] (8 rows x 512B contiguous),
// combine with per-relation basis coefficients * norm, atomicAdd into out[dst].
// ---------------------------------------------------------------------------
__global__ __launch_bounds__(256) void k_edge(
    const int* __restrict__ src, const int* __restrict__ dst,
    const int* __restrict__ etype, const float* __restrict__ norm,
    const float* __restrict__ wcomp, const float* __restrict__ hb,
    float* __restrict__ out, int E)
{
  int e = blockIdx.x * 4 + (threadIdx.x >> 6);
  if (e >= E) return;
  int lane = threadIdx.x & 63;
  int s  = src[e];
  int d_ = dst[e];
  int tp = etype[e];
  float nm = norm[e];

  float c[NB];
  #pragma unroll
  for (int b = 0; b < NB; b++) c[b] = wcomp[tp * NB + b] * nm;

  const float* hrow = hb + (size_t)s * (NB * DD);
  float2 acc = make_float2(0.f, 0.f);
  #pragma unroll
  for (int b = 0; b < NB; b++) {
    float2 v = *(const float2*)&hrow[b * DD + lane * 2];
    acc.x += c[b] * v.x;
    acc.y += c[b] * v.y;
  }
  float* op = &out[(size_t)d_ * DD + lane * 2];
  atomicAdd(op,     acc.x);
  atomicAdd(op + 1, acc.y);
}

__global__ __launch_bounds__(256) void k_relu(float* __restrict__ x, int n4)
{
  int i = blockIdx.x * 256 + threadIdx.x;
  if (i < n4) {
    float4 v = ((float4*)x)[i];
    v.x = fmaxf(v.x, 0.f); v.y = fmaxf(v.y, 0.f);
    v.z = fmaxf(v.z, 0.f); v.w = fmaxf(v.w, 0.f);
    ((float4*)x)[i] = v;
  }
}

extern "C" void kernel_launch(void* const* d_in, const int* in_sizes, int n_in,
                              void* d_out, int out_size, void* d_ws, size_t ws_size,
                              hipStream_t stream)
{
  const int*   h_ids     = (const int*)d_in[0];
  const int*   src       = (const int*)d_in[1];
  const int*   dst       = (const int*)d_in[2];
  const int*   etype     = (const int*)d_in[3];
  const float* norm      = (const float*)d_in[4];
  const float* embedding = (const float*)d_in[5];
  const float* w_comp1   = (const float*)d_in[6];
  const float* bases1    = (const float*)d_in[7];
  const float* loop_w1   = (const float*)d_in[8];
  const float* bias1     = (const float*)d_in[9];
  const float* w_comp2   = (const float*)d_in[10];
  const float* bases2    = (const float*)d_in[11];
  const float* loop_w2   = (const float*)d_in[12];
  const float* bias2     = (const float*)d_in[13];

  const int N = in_sizes[0];
  const int E = in_sizes[1];

  // workspace: hb [N,8,128] fp32 (204.8 MB) + h1 [N,128] fp32 (25.6 MB)
  float* hb = (float*)d_ws;
  float* h1 = hb + (size_t)N * NB * DD;
  float* out = (float*)d_out;

  dim3 gg((N + 63) / 64, NB + 1);
  dim3 ge((E + 3) / 4);
  int relu_n4 = N * DD / 4;

  // ---- layer 1 (relu) ----
  k_gemm<<<gg, 256, 0, stream>>>(embedding, h_ids, bases1, loop_w1, bias1, hb, h1, N);
  k_edge<<<ge, 256, 0, stream>>>(src, dst, etype, norm, w_comp1, hb, h1, E);
  k_relu<<<(relu_n4 + 255) / 256, 256, 0, stream>>>(h1, relu_n4);

  // ---- layer 2 (no act) ----
  k_gemm<<<gg, 256, 0, stream>>>(h1, nullptr, bases2, loop_w2, bias2, hb, out, N);
  k_edge<<<ge, 256, 0, stream>>>(src, dst, etype, norm, w_comp2, hb, out, E);
}

// Round 2
// 1405.911 us; speedup vs baseline: 1.0922x; 1.0922x over previous
//
#include <hip/hip_runtime.h>
#include <hip/hip_bf16.h>

#define DD 128   // feature dim
#define NB 8     // num bases

typedef unsigned short ushort_t;
typedef unsigned int uint_t;

// ---------------------------------------------------------------------------
// GEMM: for blockIdx.y = m in [0,9):
//   m < 8 : hb[n, m, :]   = bf16( h[n,:] @ bases[m] )   (basis transform)
//   m == 8: selfout[n, :] = h[n,:] @ loop_w + bias      (fp32, init out)
// Block tile: 64 nodes x 128 outputs, 256 threads, 4x8 register tile/thread.
// ---------------------------------------------------------------------------
__global__ __launch_bounds__(256) void k_gemm(
    const float* __restrict__ h, const int* __restrict__ ids,
    const float* __restrict__ bases, const float* __restrict__ loopw,
    const float* __restrict__ bias,
    ushort_t* __restrict__ hb, float* __restrict__ selfout, int N)
{
  __shared__ float sW[32][128];   // 16 KB: W k-chunk
  __shared__ float sH[32][64];    // 8 KB: h chunk, transposed [k][node]

  const int m = blockIdx.y;
  const float* __restrict__ W = (m < NB) ? (bases + (size_t)m * DD * DD) : loopw;
  const int n0 = blockIdx.x * 64;
  const int t  = threadIdx.x;
  const int tx = t & 15;          // output group: o = tx*8 .. tx*8+8
  const int ty = t >> 4;          // node group:   n = n0 + ty*4 .. +4

  float acc[4][8] = {};

  for (int k0 = 0; k0 < DD; k0 += 32) {
    for (int i = t; i < 1024; i += 256)
      ((float4*)sW)[i] = ((const float4*)(W + (size_t)k0 * DD))[i];
    {
      int nn = t >> 2;
      int kk = (t & 3) * 8;
      int row = n0 + nn; if (row >= N) row = N - 1;   // clamp (writes guarded)
      if (ids) row = ids[row];
      const float* hp = h + (size_t)row * DD + k0 + kk;
      float4 v0 = *(const float4*)hp;
      float4 v1 = *(const float4*)(hp + 4);
      sH[kk+0][nn]=v0.x; sH[kk+1][nn]=v0.y; sH[kk+2][nn]=v0.z; sH[kk+3][nn]=v0.w;
      sH[kk+4][nn]=v1.x; sH[kk+5][nn]=v1.y; sH[kk+6][nn]=v1.z; sH[kk+7][nn]=v1.w;
    }
    __syncthreads();
    #pragma unroll
    for (int kk = 0; kk < 32; kk++) {
      float hv[4], wv[8];
      *(float4*)hv     = *(const float4*)&sH[kk][ty*4];
      *(float4*)&wv[0] = *(const float4*)&sW[kk][tx*8];
      *(float4*)&wv[4] = *(const float4*)&sW[kk][tx*8+4];
      #pragma unroll
      for (int a = 0; a < 4; a++)
        #pragma unroll
        for (int bb = 0; bb < 8; bb++)
          acc[a][bb] += hv[a] * wv[bb];
    }
    __syncthreads();
  }

  #pragma unroll
  for (int a = 0; a < 4; a++) {
    int n = n0 + ty*4 + a;
    if (n >= N) continue;
    if (m < NB) {
      union { ushort_t u[8]; uint4 v; } p;
      #pragma unroll
      for (int bb = 0; bb < 8; bb++) {
        __hip_bfloat16 bv = __float2bfloat16(acc[a][bb]);
        p.u[bb] = *(ushort_t*)&bv;
      }
      *(uint4*)&hb[((size_t)n * NB + m) * DD + tx*8] = p.v;
    } else {
      float o[8];
      #pragma unroll
      for (int bb = 0; bb < 8; bb++) o[bb] = acc[a][bb] + bias[tx*8 + bb];
      float4* dst = (float4*)&selfout[(size_t)n * DD + tx*8];
      dst[0] = *(float4*)&o[0];
      dst[1] = *(float4*)&o[4];
    }
  }
}

// ---------------------------------------------------------------------------
// Edge kernel: one wave per edge. Gather bf16 hb[src] (8 rows x 256B
// contiguous = 2KB/edge), combine with basis coefficients * norm,
// fp32 atomicAdd into out[dst].
// ---------------------------------------------------------------------------
__global__ __launch_bounds__(256) void k_edge(
    const int* __restrict__ src, const int* __restrict__ dst,
    const int* __restrict__ etype, const float* __restrict__ norm,
    const float* __restrict__ wcomp, const ushort_t* __restrict__ hb,
    float* __restrict__ out, int E)
{
  int e = blockIdx.x * 4 + (threadIdx.x >> 6);
  if (e >= E) return;
  int lane = threadIdx.x & 63;
  int s  = src[e];
  int d_ = dst[e];
  int tp = etype[e];
  float nm = norm[e];

  float c[NB];
  #pragma unroll
  for (int b = 0; b < NB; b++) c[b] = wcomp[tp * NB + b] * nm;

  const ushort_t* hrow = hb + (size_t)s * (NB * DD);
  float accx = 0.f, accy = 0.f;
  #pragma unroll
  for (int b = 0; b < NB; b++) {
    uint_t v = *(const uint_t*)&hrow[b * DD + lane * 2];
    float lo = __uint_as_float((v & 0xFFFFu) << 16);
    float hi = __uint_as_float(v & 0xFFFF0000u);
    accx += c[b] * lo;
    accy += c[b] * hi;
  }
  float* op = &out[(size_t)d_ * DD + lane * 2];
  atomicAdd(op,     accx);
  atomicAdd(op + 1, accy);
}

__global__ __launch_bounds__(256) void k_relu(float* __restrict__ x, int n4)
{
  int i = blockIdx.x * 256 + threadIdx.x;
  if (i < n4) {
    float4 v = ((float4*)x)[i];
    v.x = fmaxf(v.x, 0.f); v.y = fmaxf(v.y, 0.f);
    v.z = fmaxf(v.z, 0.f); v.w = fmaxf(v.w, 0.f);
    ((float4*)x)[i] = v;
  }
}

extern "C" void kernel_launch(void* const* d_in, const int* in_sizes, int n_in,
                              void* d_out, int out_size, void* d_ws, size_t ws_size,
                              hipStream_t stream)
{
  const int*   h_ids     = (const int*)d_in[0];
  const int*   src       = (const int*)d_in[1];
  const int*   dst       = (const int*)d_in[2];
  const int*   etype     = (const int*)d_in[3];
  const float* norm      = (const float*)d_in[4];
  const float* embedding = (const float*)d_in[5];
  const float* w_comp1   = (const float*)d_in[6];
  const float* bases1    = (const float*)d_in[7];
  const float* loop_w1   = (const float*)d_in[8];
  const float* bias1     = (const float*)d_in[9];
  const float* w_comp2   = (const float*)d_in[10];
  const float* bases2    = (const float*)d_in[11];
  const float* loop_w2   = (const float*)d_in[12];
  const float* bias2     = (const float*)d_in[13];

  const int N = in_sizes[0];
  const int E = in_sizes[1];

  // workspace: hb [N,8,128] bf16 (102.4 MB) + h1 [N,128] fp32 (25.6 MB)
  ushort_t* hb = (ushort_t*)d_ws;
  float*    h1 = (float*)(hb + (size_t)N * NB * DD);
  float*    out = (float*)d_out;

  dim3 gg((N + 63) / 64, NB + 1);
  dim3 ge((E + 3) / 4);
  int relu_n4 = N * DD / 4;

  // ---- layer 1 (relu) ----
  k_gemm<<<gg, 256, 0, stream>>>(embedding, h_ids, bases1, loop_w1, bias1, hb, h1, N);
  k_edge<<<ge, 256, 0, stream>>>(src, dst, etype, norm, w_comp1, hb, h1, E);
  k_relu<<<(relu_n4 + 255) / 256, 256, 0, stream>>>(h1, relu_n4);

  // ---- layer 2 (no act) ----
  k_gemm<<<gg, 256, 0, stream>>>(h1, nullptr, bases2, loop_w2, bias2, hb, out, N);
  k_edge<<<ge, 256, 0, stream>>>(src, dst, etype, norm, w_comp2, hb, out, E);
}

// Round 3
// 668.445 us; speedup vs baseline: 2.2971x; 2.1033x over previous
//
#include <hip/hip_runtime.h>
#include <hip/hip_bf16.h>

#define DD 128
#define NB 8

typedef unsigned short ushort_t;
typedef unsigned int uint_t;
typedef __attribute__((ext_vector_type(8))) short short8v;   // 8 bf16 (4 VGPRs)
typedef __attribute__((ext_vector_type(4))) float f32x4;

static __device__ __forceinline__ ushort_t f2bf(float f) {
  __hip_bfloat16 b = __float2bfloat16(f);
  return *(ushort_t*)&b;
}
static __device__ __forceinline__ float bf2f_lo(uint_t u) {
  return __uint_as_float((u & 0xFFFFu) << 16);
}
static __device__ __forceinline__ float bf2f_hi(uint_t u) {
  return __uint_as_float(u & 0xFFFF0000u);
}

// ---------------------------------------------------------------------------
// Wt[layer][m][feat][k] = bf16( W[m][k][feat] );  m<8 from bases, m==8 loop_w
// ---------------------------------------------------------------------------
__global__ __launch_bounds__(256) void k_prep_w(
    const float* __restrict__ bases1, const float* __restrict__ loopw1,
    const float* __restrict__ bases2, const float* __restrict__ loopw2,
    ushort_t* __restrict__ Wt)
{
  int i = blockIdx.x * 256 + threadIdx.x;          // over 2*9*128*128
  if (i >= 2 * 9 * 16384) return;
  int layer = i / (9 * 16384);
  int rem   = i % (9 * 16384);
  int m     = rem / 16384;
  int idx   = rem % 16384;
  int feat  = idx / 128;
  int k     = idx % 128;
  const float* basesL = layer ? bases2 : bases1;
  const float* loopwL = layer ? loopw2 : loopw1;
  float v = (m < NB) ? basesL[(size_t)m * 16384 + k * 128 + feat]
                     : loopwL[k * 128 + feat];
  Wt[i] = f2bf(v);
}

// cast h (fp32, optional ids indirection) -> bf16 [N][128]
__global__ __launch_bounds__(256) void k_cast(
    const float* __restrict__ h, const int* __restrict__ ids,
    ushort_t* __restrict__ hbf, int N)
{
  int i = blockIdx.x * 256 + threadIdx.x;          // one thread per 8 elems
  if (i >= N * (DD / 8)) return;
  int n  = i / (DD / 8);
  int k8 = (i % (DD / 8)) * 8;
  int row = ids ? ids[n] : n;
  const float* hp = h + (size_t)row * DD + k8;
  float4 v0 = *(const float4*)hp;
  float4 v1 = *(const float4*)(hp + 4);
  union { ushort_t u[8]; uint4 v; } p;
  p.u[0]=f2bf(v0.x); p.u[1]=f2bf(v0.y); p.u[2]=f2bf(v0.z); p.u[3]=f2bf(v0.w);
  p.u[4]=f2bf(v1.x); p.u[5]=f2bf(v1.y); p.u[6]=f2bf(v1.z); p.u[7]=f2bf(v1.w);
  *(uint4*)&hbf[(size_t)n * DD + k8] = p.v;
}

// ---------------------------------------------------------------------------
// MFMA GEMM: blockIdx.y = m in [0,9). 64-node tile, 128 out-feats, K=128.
// 4 waves, wave wv: feats [wv*32, wv*32+32). A = Wt (feat-major), B = h rows.
// m<8: hb[n][m][feat] bf16.  m==8: selfout[n][feat] = . + bias (fp32).
// ---------------------------------------------------------------------------
__global__ __launch_bounds__(256) void k_mm(
    const ushort_t* __restrict__ hsrc,   // [N][128] bf16
    const ushort_t* __restrict__ Wt,     // [9][128][128] bf16 feat-major
    const float* __restrict__ bias,
    ushort_t* __restrict__ hb,           // [N][8][128] bf16
    float* __restrict__ selfout, int N)
{
  const int m    = blockIdx.y;
  const int n0   = blockIdx.x * 64;
  const int wv   = threadIdx.x >> 6;
  const int lane = threadIdx.x & 63;
  const int l15  = lane & 15, l4 = lane >> 4;

  const ushort_t* Wm = Wt + (size_t)m * 16384;

  f32x4 acc[2][4];
  #pragma unroll
  for (int a = 0; a < 2; a++)
    #pragma unroll
    for (int b = 0; b < 4; b++) acc[a][b] = (f32x4)0.f;

  int nodes[4];
  #pragma unroll
  for (int nf = 0; nf < 4; nf++) {
    int n = n0 + nf * 16 + l15;
    nodes[nf] = (n < N) ? n : (N - 1);
  }

  #pragma unroll
  for (int ks = 0; ks < 4; ks++) {
    const int k0 = ks * 32;
    short8v af[2], bfr[4];
    #pragma unroll
    for (int mf = 0; mf < 2; mf++)
      af[mf] = *(const short8v*)&Wm[(wv * 32 + mf * 16 + l15) * DD + k0 + l4 * 8];
    #pragma unroll
    for (int nf = 0; nf < 4; nf++)
      bfr[nf] = *(const short8v*)&hsrc[(size_t)nodes[nf] * DD + k0 + l4 * 8];
    #pragma unroll
    for (int mf = 0; mf < 2; mf++)
      #pragma unroll
      for (int nf = 0; nf < 4; nf++)
        acc[mf][nf] = __builtin_amdgcn_mfma_f32_16x16x32_bf16(af[mf], bfr[nf], acc[mf][nf], 0, 0, 0);
  }

  // C layout: col(=node) = lane&15, row(=feat) = (lane>>4)*4 + r
  if (m < NB) {
    #pragma unroll
    for (int mf = 0; mf < 2; mf++)
      #pragma unroll
      for (int nf = 0; nf < 4; nf++) {
        int n = n0 + nf * 16 + l15;
        if (n >= N) continue;
        int feat = wv * 32 + mf * 16 + l4 * 4;
        union { ushort_t u[4]; uint2 v2; } p;
        #pragma unroll
        for (int r = 0; r < 4; r++) p.u[r] = f2bf(acc[mf][nf][r]);
        *(uint2*)&hb[(size_t)n * (NB * DD) + m * DD + feat] = p.v2;
      }
  } else {
    #pragma unroll
    for (int mf = 0; mf < 2; mf++)
      #pragma unroll
      for (int nf = 0; nf < 4; nf++) {
        int n = n0 + nf * 16 + l15;
        if (n >= N) continue;
        int feat = wv * 32 + mf * 16 + l4 * 4;
        float4 o;
        o.x = acc[mf][nf][0] + bias[feat + 0];
        o.y = acc[mf][nf][1] + bias[feat + 1];
        o.z = acc[mf][nf][2] + bias[feat + 2];
        o.w = acc[mf][nf][3] + bias[feat + 3];
        *(float4*)&selfout[(size_t)n * DD + feat] = o;
      }
  }
}

// ------------------------------- sort-by-dst -------------------------------
__global__ __launch_bounds__(256) void k_zero(int* __restrict__ p, int n)
{
  int i = blockIdx.x * 256 + threadIdx.x;
  if (i < n) p[i] = 0;
}

__global__ __launch_bounds__(256) void k_hist(
    const int* __restrict__ dst, int* __restrict__ cnt, int E)
{
  int e = blockIdx.x * 256 + threadIdx.x;
  if (e < E) atomicAdd(&cnt[dst[e]], 1);
}

__global__ __launch_bounds__(256) void k_bsum(
    const int* __restrict__ cnt, int* __restrict__ bsum, int N)
{
  __shared__ int s[256];
  int i = blockIdx.x * 256 + threadIdx.x;
  s[threadIdx.x] = (i < N) ? cnt[i] : 0;
  __syncthreads();
  for (int off = 128; off > 0; off >>= 1) {
    if (threadIdx.x < off) s[threadIdx.x] += s[threadIdx.x + off];
    __syncthreads();
  }
  if (threadIdx.x == 0) bsum[blockIdx.x] = s[0];
}

__global__ __launch_bounds__(256) void k_scanb(
    const int* __restrict__ bsum, int* __restrict__ boff, int nb)
{
  __shared__ int s[256];
  int t = threadIdx.x;
  int own = (t < nb) ? bsum[t] : 0;
  s[t] = own;
  __syncthreads();
  for (int off = 1; off < 256; off <<= 1) {
    int v = (t >= off) ? s[t - off] : 0;
    __syncthreads();
    s[t] += v;
    __syncthreads();
  }
  if (t < nb) boff[t] = s[t] - own;     // exclusive
}

__global__ __launch_bounds__(256) void k_scan3(
    const int* __restrict__ cnt, const int* __restrict__ boff,
    int* __restrict__ row_start, int N)
{
  __shared__ int s[256];
  int t = threadIdx.x;
  int i = blockIdx.x * 256 + t;
  int v = (i < N) ? cnt[i] : 0;
  s[t] = v;
  __syncthreads();
  for (int off = 1; off < 256; off <<= 1) {
    int u = (t >= off) ? s[t - off] : 0;
    __syncthreads();
    s[t] += u;
    __syncthreads();
  }
  if (i < N) row_start[i] = boff[blockIdx.x] + s[t] - v;
}

__global__ __launch_bounds__(256) void k_place(
    const int* __restrict__ dst, const int* __restrict__ row_start,
    int* __restrict__ cursor, int* __restrict__ perm, int E)
{
  int e = blockIdx.x * 256 + threadIdx.x;
  if (e < E) {
    int v = dst[e];
    int slot = row_start[v] + atomicAdd(&cursor[v], 1);
    perm[slot] = e;
  }
}

// ---------------------------------------------------------------------------
// Aggregation: one wave per dst node, zero atomics. lane covers 2 feats.
// out = selfin + sum_edges; LAYER==1: relu -> bf16 h1b; LAYER==2: fp32 out.
// ---------------------------------------------------------------------------
template <int LAYER>
__global__ __launch_bounds__(256) void k_agg(
    const int* __restrict__ perm, const int* __restrict__ row_start,
    const int* __restrict__ cnt,
    const int* __restrict__ src, const int* __restrict__ etype,
    const float* __restrict__ norm, const float* __restrict__ wcomp,
    const ushort_t* __restrict__ hb,
    const float* __restrict__ selfin,
    float* __restrict__ outf, ushort_t* __restrict__ outb, int N)
{
  int v = blockIdx.x * 4 + (threadIdx.x >> 6);
  if (v >= N) return;
  int lane = threadIdx.x & 63;
  int beg = row_start[v];
  int num = cnt[v];

  float ax = 0.f, ay = 0.f;
  const ushort_t* hbL = hb + lane * 2;
  for (int i = 0; i < num; i++) {
    int e = perm[beg + i];
    int s = src[e];
    int tp = etype[e];
    float nm = norm[e];
    const float* wr = wcomp + tp * NB;
    const uint_t* hr = (const uint_t*)(hbL + (size_t)s * (NB * DD));
    #pragma unroll
    for (int b = 0; b < NB; b++) {
      float c = wr[b] * nm;
      uint_t u = hr[b * (DD / 2)];
      ax += c * bf2f_lo(u);
      ay += c * bf2f_hi(u);
    }
  }

  float2 sv = *(const float2*)&selfin[(size_t)v * DD + lane * 2];
  ax += sv.x; ay += sv.y;
  if (LAYER == 1) {
    ax = fmaxf(ax, 0.f);
    ay = fmaxf(ay, 0.f);
    union { ushort_t u[2]; uint_t w; } p;
    p.u[0] = f2bf(ax); p.u[1] = f2bf(ay);
    *(uint_t*)&outb[(size_t)v * DD + lane * 2] = p.w;
  } else {
    *(float2*)&outf[(size_t)v * DD + lane * 2] = make_float2(ax, ay);
  }
}

extern "C" void kernel_launch(void* const* d_in, const int* in_sizes, int n_in,
                              void* d_out, int out_size, void* d_ws, size_t ws_size,
                              hipStream_t stream)
{
  const int*   h_ids     = (const int*)d_in[0];
  const int*   src       = (const int*)d_in[1];
  const int*   dst       = (const int*)d_in[2];
  const int*   etype     = (const int*)d_in[3];
  const float* norm      = (const float*)d_in[4];
  const float* embedding = (const float*)d_in[5];
  const float* w_comp1   = (const float*)d_in[6];
  const float* bases1    = (const float*)d_in[7];
  const float* loop_w1   = (const float*)d_in[8];
  const float* bias1     = (const float*)d_in[9];
  const float* w_comp2   = (const float*)d_in[10];
  const float* bases2    = (const float*)d_in[11];
  const float* loop_w2   = (const float*)d_in[12];
  const float* bias2     = (const float*)d_in[13];

  const int N = in_sizes[0];
  const int E = in_sizes[1];
  const int NBLK = (N + 255) / 256;     // <= 256 assumed (N <= 65536)

  // ---- workspace carve-up (256B aligned) ----
  char* base = (char*)d_ws;
  size_t off = 0;
  auto alloc = [&](size_t bytes) -> char* {
    char* p = base + off;
    off += (bytes + 255) & ~(size_t)255;
    return p;
  };
  ushort_t* hb     = (ushort_t*)alloc((size_t)N * NB * DD * 2);  // 102.4 MB
  ushort_t* hbf    = (ushort_t*)alloc((size_t)N * DD * 2);       // 12.8 MB
  ushort_t* h1b    = (ushort_t*)alloc((size_t)N * DD * 2);       // 12.8 MB
  float*    h1self = (float*)   alloc((size_t)N * DD * 4);       // 25.6 MB
  ushort_t* Wt     = (ushort_t*)alloc((size_t)2 * 9 * 16384 * 2);
  int*      cnt    = (int*)     alloc((size_t)2 * N * 4);        // cnt + cursor
  int*      cursor = cnt + N;
  int*      rowst  = (int*)     alloc((size_t)N * 4);
  int*      bsum   = (int*)     alloc(256 * 4);
  int*      boff   = (int*)     alloc(256 * 4);
  int*      perm   = (int*)     alloc((size_t)E * 4);
  float*    out    = (float*)d_out;

  // ---- build CSR by dst (once; reused by both layers) ----
  k_zero <<<(2 * N + 255) / 256, 256, 0, stream>>>(cnt, 2 * N);
  k_hist <<<(E + 255) / 256, 256, 0, stream>>>(dst, cnt, E);
  k_bsum <<<NBLK, 256, 0, stream>>>(cnt, bsum, N);
  k_scanb<<<1, 256, 0, stream>>>(bsum, boff, NBLK);
  k_scan3<<<NBLK, 256, 0, stream>>>(cnt, boff, rowst, N);
  k_place<<<(E + 255) / 256, 256, 0, stream>>>(dst, rowst, cursor, perm, E);

  // ---- weights -> bf16 transposed ----
  k_prep_w<<<(2 * 9 * 16384 + 255) / 256, 256, 0, stream>>>(bases1, loop_w1, bases2, loop_w2, Wt);

  dim3 gmm((N + 63) / 64, NB + 1);
  int gagg = (N + 3) / 4;

  // ---- layer 1 ----
  k_cast<<<(N * (DD / 8) + 255) / 256, 256, 0, stream>>>(embedding, h_ids, hbf, N);
  k_mm  <<<gmm, 256, 0, stream>>>(hbf, Wt, bias1, hb, h1self, N);
  k_agg<1><<<gagg, 256, 0, stream>>>(perm, rowst, cnt, src, etype, norm, w_comp1,
                                     hb, h1self, nullptr, h1b, N);

  // ---- layer 2 ----
  k_mm  <<<gmm, 256, 0, stream>>>(h1b, Wt + 9 * 16384, bias2, hb, out, N);
  k_agg<2><<<gagg, 256, 0, stream>>>(perm, rowst, cnt, src, etype, norm, w_comp2,
                                     hb, out, out, nullptr, N);
}

// Round 4
// 500.269 us; speedup vs baseline: 3.0694x; 1.3362x over previous
//
#include <hip/hip_runtime.h>

#define DD 128
#define NB 8
#define KTOT 1152   // 1024 (agg: k = kk*8 + b) + 128 (self-loop h)

typedef unsigned short ushort_t;
typedef unsigned int uint_t;
typedef __attribute__((ext_vector_type(8))) _Float16 half8v;
typedef __attribute__((ext_vector_type(4))) float f32x4;

// ---------------------------------------------------------------------------
// Wc[layer][feat][k]: k<1024 -> bases[b=k&7][kk=k>>3][feat]; else loop_w[k-1024][feat]
// ---------------------------------------------------------------------------
__global__ __launch_bounds__(256) void k_prep_w(
    const float* __restrict__ bases1, const float* __restrict__ loopw1,
    const float* __restrict__ bases2, const float* __restrict__ loopw2,
    _Float16* __restrict__ Wc)
{
  int i = blockIdx.x * 256 + threadIdx.x;          // 2*128*1152
  if (i >= 2 * DD * KTOT) return;
  int layer = i / (DD * KTOT);
  int rem   = i % (DD * KTOT);
  int feat  = rem / KTOT;
  int k     = rem % KTOT;
  const float* basesL = layer ? bases2 : bases1;
  const float* loopwL = layer ? loopw2 : loopw1;
  float v;
  if (k < 1024) {
    int kk = k >> 3, b = k & 7;
    v = basesL[((size_t)b * DD + kk) * DD + feat];
  } else {
    v = loopwL[(size_t)(k - 1024) * DD + feat];
  }
  Wc[i] = (_Float16)v;
}

// cast h (fp32, optional ids indirection) -> fp16 [N][128]
__global__ __launch_bounds__(256) void k_cast(
    const float* __restrict__ h, const int* __restrict__ ids,
    _Float16* __restrict__ hf, int N)
{
  int i = blockIdx.x * 256 + threadIdx.x;          // one thread per 8 elems
  if (i >= N * (DD / 8)) return;
  int n  = i / (DD / 8);
  int k8 = (i % (DD / 8)) * 8;
  int row = ids ? ids[n] : n;
  const float* hp = h + (size_t)row * DD + k8;
  float4 v0 = *(const float4*)hp;
  float4 v1 = *(const float4*)(hp + 4);
  union { _Float16 e[8]; uint4 q; } p;
  p.e[0]=(_Float16)v0.x; p.e[1]=(_Float16)v0.y; p.e[2]=(_Float16)v0.z; p.e[3]=(_Float16)v0.w;
  p.e[4]=(_Float16)v1.x; p.e[5]=(_Float16)v1.y; p.e[6]=(_Float16)v1.z; p.e[7]=(_Float16)v1.w;
  *(uint4*)&hf[(size_t)n * DD + k8] = p.q;
}

// ------------------------------- sort-by-dst -------------------------------
__global__ __launch_bounds__(256) void k_zero(int* __restrict__ p, int n)
{
  int i = blockIdx.x * 256 + threadIdx.x;
  if (i < n) p[i] = 0;
}

__global__ __launch_bounds__(256) void k_hist(
    const int* __restrict__ dst, int* __restrict__ cnt, int E)
{
  int e = blockIdx.x * 256 + threadIdx.x;
  if (e < E) atomicAdd(&cnt[dst[e]], 1);
}

__global__ __launch_bounds__(256) void k_bsum(
    const int* __restrict__ cnt, int* __restrict__ bsum, int N)
{
  __shared__ int s[256];
  int i = blockIdx.x * 256 + threadIdx.x;
  s[threadIdx.x] = (i < N) ? cnt[i] : 0;
  __syncthreads();
  for (int off = 128; off > 0; off >>= 1) {
    if (threadIdx.x < off) s[threadIdx.x] += s[threadIdx.x + off];
    __syncthreads();
  }
  if (threadIdx.x == 0) bsum[blockIdx.x] = s[0];
}

__global__ __launch_bounds__(256) void k_scanb(
    const int* __restrict__ bsum, int* __restrict__ boff, int nb)
{
  __shared__ int s[256];
  int t = threadIdx.x;
  int own = (t < nb) ? bsum[t] : 0;
  s[t] = own;
  __syncthreads();
  for (int off = 1; off < 256; off <<= 1) {
    int v = (t >= off) ? s[t - off] : 0;
    __syncthreads();
    s[t] += v;
    __syncthreads();
  }
  if (t < nb) boff[t] = s[t] - own;     // exclusive
}

__global__ __launch_bounds__(256) void k_scan3(
    const int* __restrict__ cnt, const int* __restrict__ boff,
    int* __restrict__ row_start, int N)
{
  __shared__ int s[256];
  int t = threadIdx.x;
  int i = blockIdx.x * 256 + t;
  int v = (i < N) ? cnt[i] : 0;
  s[t] = v;
  __syncthreads();
  for (int off = 1; off < 256; off <<= 1) {
    int u = (t >= off) ? s[t - off] : 0;
    __syncthreads();
    s[t] += u;
    __syncthreads();
  }
  if (i < N) row_start[i] = boff[blockIdx.x] + s[t] - v;
}

__global__ __launch_bounds__(256) void k_place(
    const int* __restrict__ dst, const int* __restrict__ row_start,
    int* __restrict__ cursor, int* __restrict__ perm, int E)
{
  int e = blockIdx.x * 256 + threadIdx.x;
  if (e < E) {
    int v = dst[e];
    int slot = row_start[v] + atomicAdd(&cursor[v], 1);
    perm[slot] = e;
  }
}

// ---------------------------------------------------------------------------
// Pre-transform aggregation: one wave per dst node, zero atomics.
// agg[v][kk*8+b] = sum_{e->v} wcomp[et[e],b]*norm[e] * h[src[e]][kk]   (fp16)
// Gather is only 256B/edge from the 12.8MB h buffer (L2/L3 resident).
// ---------------------------------------------------------------------------
__global__ __launch_bounds__(256) void k_agg(
    const int* __restrict__ perm, const int* __restrict__ row_start,
    const int* __restrict__ cnt,
    const int* __restrict__ src, const int* __restrict__ etype,
    const float* __restrict__ norm, const float* __restrict__ wcomp,
    const _Float16* __restrict__ hf,
    _Float16* __restrict__ agg, int N)
{
  int v = blockIdx.x * 4 + (threadIdx.x >> 6);
  if (v >= N) return;
  int lane = threadIdx.x & 63;
  int beg = row_start[v];
  int num = cnt[v];

  float ax[NB] = {}, ay[NB] = {};
  for (int i = 0; i < num; i++) {
    int e = perm[beg + i];
    int s = src[e];
    int tp = etype[e];
    float nm = norm[e];
    union { uint_t u; _Float16 h[2]; } cv;
    cv.u = *(const uint_t*)&hf[(size_t)s * DD + lane * 2];
    float lo = (float)cv.h[0], hi = (float)cv.h[1];
    const float* wr = wcomp + tp * NB;
    #pragma unroll
    for (int b = 0; b < NB; b++) {
      float c = wr[b] * nm;
      ax[b] += c * lo;
      ay[b] += c * hi;
    }
  }

  // lane owns feats kk0=lane*2 (ax) and kk1=lane*2+1 (ay)
  // -> k positions lane*16+b and lane*16+8+b: one 32B contiguous chunk
  union { _Float16 e[8]; uint4 q; } p0, p1;
  #pragma unroll
  for (int b = 0; b < NB; b++) { p0.e[b] = (_Float16)ax[b]; p1.e[b] = (_Float16)ay[b]; }
  uint4* dstp = (uint4*)&agg[(size_t)v * 1024 + lane * 16];
  dstp[0] = p0.q;
  dstp[1] = p1.q;
}

// ---------------------------------------------------------------------------
// MFMA GEMM, K=1152: out[v][feat] = sum_k Bcomb[v][k]*Wc[feat][k] + bias
// Bcomb = [agg[v] (1024) | hf[v] (128)].  64-node tile, 4 waves over feats.
// LAYER==1: relu -> fp16 outh.  LAYER==2: fp32 outf.
// ---------------------------------------------------------------------------
template <int LAYER>
__global__ __launch_bounds__(256) void k_mm(
    const _Float16* __restrict__ agg,   // [N][1024]
    const _Float16* __restrict__ hf,    // [N][128]
    const _Float16* __restrict__ Wc,    // [128][1152] feat-major
    const float* __restrict__ bias,
    float* __restrict__ outf, _Float16* __restrict__ outh, int N)
{
  const int n0   = blockIdx.x * 64;
  const int wv   = threadIdx.x >> 6;
  const int lane = threadIdx.x & 63;
  const int l15  = lane & 15, l4 = lane >> 4;

  f32x4 acc[2][4];
  #pragma unroll
  for (int a = 0; a < 2; a++)
    #pragma unroll
    for (int b = 0; b < 4; b++) acc[a][b] = (f32x4)0.f;

  int nodes[4];
  #pragma unroll
  for (int nf = 0; nf < 4; nf++) {
    int n = n0 + nf * 16 + l15;
    nodes[nf] = (n < N) ? n : (N - 1);
  }

  #pragma unroll
  for (int ks = 0; ks < KTOT / 32; ks++) {
    const int k0 = ks * 32;
    half8v af[2], bfr[4];
    #pragma unroll
    for (int mf = 0; mf < 2; mf++)
      af[mf] = *(const half8v*)&Wc[(size_t)(wv * 32 + mf * 16 + l15) * KTOT + k0 + l4 * 8];
    #pragma unroll
    for (int nf = 0; nf < 4; nf++) {
      if (ks < 32)
        bfr[nf] = *(const half8v*)&agg[(size_t)nodes[nf] * 1024 + k0 + l4 * 8];
      else
        bfr[nf] = *(const half8v*)&hf[(size_t)nodes[nf] * DD + (k0 - 1024) + l4 * 8];
    }
    #pragma unroll
    for (int mf = 0; mf < 2; mf++)
      #pragma unroll
      for (int nf = 0; nf < 4; nf++)
        acc[mf][nf] = __builtin_amdgcn_mfma_f32_16x16x32_f16(af[mf], bfr[nf], acc[mf][nf], 0, 0, 0);
  }

  // C layout: col(=node) = lane&15, row(=feat) = (lane>>4)*4 + r
  #pragma unroll
  for (int mf = 0; mf < 2; mf++)
    #pragma unroll
    for (int nf = 0; nf < 4; nf++) {
      int n = n0 + nf * 16 + l15;
      if (n >= N) continue;
      int feat = wv * 32 + mf * 16 + l4 * 4;
      if (LAYER == 1) {
        union { _Float16 e[4]; uint2 q; } p;
        #pragma unroll
        for (int r = 0; r < 4; r++)
          p.e[r] = (_Float16)fmaxf(acc[mf][nf][r] + bias[feat + r], 0.f);
        *(uint2*)&outh[(size_t)n * DD + feat] = p.q;
      } else {
        float4 o;
        o.x = acc[mf][nf][0] + bias[feat + 0];
        o.y = acc[mf][nf][1] + bias[feat + 1];
        o.z = acc[mf][nf][2] + bias[feat + 2];
        o.w = acc[mf][nf][3] + bias[feat + 3];
        *(float4*)&outf[(size_t)n * DD + feat] = o;
      }
    }
}

extern "C" void kernel_launch(void* const* d_in, const int* in_sizes, int n_in,
                              void* d_out, int out_size, void* d_ws, size_t ws_size,
                              hipStream_t stream)
{
  const int*   h_ids     = (const int*)d_in[0];
  const int*   src       = (const int*)d_in[1];
  const int*   dst       = (const int*)d_in[2];
  const int*   etype     = (const int*)d_in[3];
  const float* norm      = (const float*)d_in[4];
  const float* embedding = (const float*)d_in[5];
  const float* w_comp1   = (const float*)d_in[6];
  const float* bases1    = (const float*)d_in[7];
  const float* loop_w1   = (const float*)d_in[8];
  const float* bias1     = (const float*)d_in[9];
  const float* w_comp2   = (const float*)d_in[10];
  const float* bases2    = (const float*)d_in[11];
  const float* loop_w2   = (const float*)d_in[12];
  const float* bias2     = (const float*)d_in[13];

  const int N = in_sizes[0];
  const int E = in_sizes[1];
  const int NBLK = (N + 255) / 256;     // <= 256 (N <= 65536)

  // ---- workspace carve-up (256B aligned) ----
  char* base = (char*)d_ws;
  size_t off = 0;
  auto alloc = [&](size_t bytes) -> char* {
    char* p = base + off;
    off += (bytes + 255) & ~(size_t)255;
    return p;
  };
  _Float16* agg  = (_Float16*)alloc((size_t)N * 1024 * 2);   // 102.4 MB
  _Float16* hfp  = (_Float16*)alloc((size_t)N * DD * 2);     // 12.8 MB
  _Float16* h1h  = (_Float16*)alloc((size_t)N * DD * 2);     // 12.8 MB
  _Float16* Wc   = (_Float16*)alloc((size_t)2 * DD * KTOT * 2);
  int*      cnt    = (int*)   alloc((size_t)2 * N * 4);      // cnt + cursor
  int*      cursor = cnt + N;
  int*      rowst  = (int*)   alloc((size_t)N * 4);
  int*      bsum   = (int*)   alloc(256 * 4);
  int*      boff   = (int*)   alloc(256 * 4);
  int*      perm   = (int*)   alloc((size_t)E * 4);
  float*    out    = (float*)d_out;

  // ---- build CSR by dst (reused by both layers) ----
  k_zero <<<(2 * N + 255) / 256, 256, 0, stream>>>(cnt, 2 * N);
  k_hist <<<(E + 255) / 256, 256, 0, stream>>>(dst, cnt, E);
  k_bsum <<<NBLK, 256, 0, stream>>>(cnt, bsum, N);
  k_scanb<<<1, 256, 0, stream>>>(bsum, boff, NBLK);
  k_scan3<<<NBLK, 256, 0, stream>>>(cnt, boff, rowst, N);
  k_place<<<(E + 255) / 256, 256, 0, stream>>>(dst, rowst, cursor, perm, E);

  // ---- weights -> fp16 combined/transposed ----
  k_prep_w<<<(2 * DD * KTOT + 255) / 256, 256, 0, stream>>>(bases1, loop_w1, bases2, loop_w2, Wc);

  dim3 gmm((N + 63) / 64);
  int gagg = (N + 3) / 4;

  // ---- layer 1 ----
  k_cast<<<(N * (DD / 8) + 255) / 256, 256, 0, stream>>>(embedding, h_ids, hfp, N);
  k_agg<<<gagg, 256, 0, stream>>>(perm, rowst, cnt, src, etype, norm, w_comp1, hfp, agg, N);
  k_mm<1><<<gmm, 256, 0, stream>>>(agg, hfp, Wc, bias1, nullptr, h1h, N);

  // ---- layer 2 ----
  k_agg<<<gagg, 256, 0, stream>>>(perm, rowst, cnt, src, etype, norm, w_comp2, h1h, agg, N);
  k_mm<2><<<gmm, 256, 0, stream>>>(agg, h1h, Wc + (size_t)DD * KTOT, bias2, out, nullptr, N);
}